// Round 1
// baseline (932.838 us; speedup 1.0000x reference)
//
#include <hip/hip_runtime.h>

// Problem constants (match reference)
#define NX_ 432
#define NY_ 496
#define C_  64
#define B_  4
#define CELLS_ (NX_ * NY_)            // 214272 cells per (bin, batch) canvas plane
#define PLANE_ ((size_t)CELLS_)       // c-plane stride in floats
#define BATCH_STRIDE_ ((size_t)C_ * CELLS_)        // 13,713,408 floats
#define BIN_STRIDE_   ((size_t)B_ * C_ * CELLS_)   // 54,853,632 floats
#define MAP_BIN_ ((size_t)B_ * CELLS_)             // map entries per bin

typedef float vfloat4 __attribute__((ext_vector_type(4)));
typedef int   vint4   __attribute__((ext_vector_type(4)));

// ---------------------------------------------------------------------------
// Kernel 1: scatter pillar index p into map[bin][b*CELLS + z + y*NX + x]
// ---------------------------------------------------------------------------
__global__ __launch_bounds__(256) void scatter_idx_kernel(
    const int* __restrict__ coords0,
    const int* __restrict__ coords1,
    const int* __restrict__ coords2,
    int* __restrict__ map, int npil)
{
    const int bin = blockIdx.y;
    const int p = blockIdx.x * 256 + threadIdx.x;
    if (p >= npil) return;
    const int* coords = (bin == 0) ? coords0 : (bin == 1) ? coords1 : coords2;
    vint4 c = ((const vint4*)coords)[p];
    size_t idx = (size_t)bin * MAP_BIN_ + (size_t)c.x * CELLS_ + c.y + c.z * NX_ + c.w;
    map[idx] = p;
}

// ---------------------------------------------------------------------------
// Kernel 2: dense gather pass. Each thread owns 8 consecutive cells; writes
// all 64 c-planes with coalesced 2x float4 nontemporal stores per plane.
//
// Software-pipelined: the row-chunk loads for plane-group g+1 are issued
// BEFORE the stores of group g, so the vmcnt wait for the next group's data
// does not require draining the older NT stores (vmcnt retires oldest-first;
// loads issued before stores can be waited on with stores still in flight).
//
// Branchless loads: invalid idx (<0) is clamped to row 0 (always-safe
// address), loaded unconditionally, zero selected in AFTER the load.
// ---------------------------------------------------------------------------
__global__ __launch_bounds__(256, 4) void gather_kernel(
    const float* __restrict__ pf0,
    const float* __restrict__ pf1,
    const float* __restrict__ pf2,
    const int* __restrict__ map,
    float* __restrict__ out)
{
    const int bin = blockIdx.z;
    const int b   = blockIdx.y;
    // CELLS_ % 8 == 0 -> no partial octets; a thread is fully valid or fully out.
    const int cell = (blockIdx.x * 256 + threadIdx.x) * 8;
    if (cell >= CELLS_) return;

    const float* __restrict__ pf = (bin == 0) ? pf0 : (bin == 1) ? pf1 : pf2;

    const int* m = map + (size_t)bin * MAP_BIN_ + (size_t)b * CELLS_ + cell;
    vint4 ia = ((const vint4*)m)[0];
    vint4 ib = ((const vint4*)m)[1];

    const int id[8] = { ia.x, ia.y, ia.z, ia.w, ib.x, ib.y, ib.z, ib.w };
    bool v[8];
    const float* r[8];
#pragma unroll
    for (int j = 0; j < 8; ++j) {
        v[j] = id[j] >= 0;
        r[j] = pf + (size_t)(v[j] ? id[j] : 0) * C_;   // clamp to row 0: safe addr
    }

    float* o = out + (size_t)bin * BIN_STRIDE_ + (size_t)b * BATCH_STRIDE_ + cell;

    // 16 groups of 4 planes. cur/nxt each hold 8 rows x float4 (planes c..c+3).
    vfloat4 cur[8], nxt[8];
#pragma unroll
    for (int j = 0; j < 8; ++j)
        cur[j] = *(const vfloat4*)(r[j]);              // group 0 preload

#pragma unroll
    for (int g = 0; g < 16; ++g) {
        if (g < 15) {
            // Issue next group's loads BEFORE this group's stores.
#pragma unroll
            for (int j = 0; j < 8; ++j)
                nxt[j] = *(const vfloat4*)(r[j] + (g + 1) * 4);
        }
        // Transpose-select-store: plane q of this group takes element q of
        // each row's float4. Two float4 stores cover the thread's 8 cells.
#pragma unroll
        for (int q = 0; q < 4; ++q) {
            vfloat4 w0, w1;
            w0.x = v[0] ? cur[0][q] : 0.0f;
            w0.y = v[1] ? cur[1][q] : 0.0f;
            w0.z = v[2] ? cur[2][q] : 0.0f;
            w0.w = v[3] ? cur[3][q] : 0.0f;
            w1.x = v[4] ? cur[4][q] : 0.0f;
            w1.y = v[5] ? cur[5][q] : 0.0f;
            w1.z = v[6] ? cur[6][q] : 0.0f;
            w1.w = v[7] ? cur[7][q] : 0.0f;
            float* po = o + (size_t)(4 * g + q) * PLANE_;
            __builtin_nontemporal_store(w0, (vfloat4*)(po));
            __builtin_nontemporal_store(w1, (vfloat4*)(po + 4));
        }
        if (g < 15) {
#pragma unroll
            for (int j = 0; j < 8; ++j)
                cur[j] = nxt[j];
        }
    }
}

extern "C" void kernel_launch(void* const* d_in, const int* in_sizes, int n_in,
                              void* d_out, int out_size, void* d_ws, size_t ws_size,
                              hipStream_t stream) {
    const float* pf0 = (const float*)d_in[0];
    const int*   co0 = (const int*)d_in[1];
    const float* pf1 = (const float*)d_in[2];
    const int*   co1 = (const int*)d_in[3];
    const float* pf2 = (const float*)d_in[4];
    const int*   co2 = (const int*)d_in[5];
    float* out = (float*)d_out;

    const int npil = in_sizes[1] / 4;   // rows in coords (B*P_PER)

    int* map = (int*)d_ws;
    const size_t map_bytes = 3 * MAP_BIN_ * sizeof(int);

    // init map to -1 (0xFFFFFFFF) — ~10 MB, ~2 us
    (void)hipMemsetAsync(map, 0xFF, map_bytes, stream);

    dim3 g1((npil + 255) / 256, 3, 1);
    scatter_idx_kernel<<<g1, 256, 0, stream>>>(co0, co1, co2, map, npil);

    // 8 cells/thread: 26784 threads per (bin,b) -> 105 blocks of 256
    dim3 g2((CELLS_ / 8 + 255) / 256, B_, 3);
    gather_kernel<<<g2, 256, 0, stream>>>(pf0, pf1, pf2, map, out);
}

// Round 2
// 701.084 us; speedup vs baseline: 1.3306x; 1.3306x over previous
//
#include <hip/hip_runtime.h>

// Problem constants (match reference)
#define NX_ 432
#define NY_ 496
#define C_  64
#define B_  4
#define CELLS_ (NX_ * NY_)            // 214272 cells per (bin, batch) canvas plane
#define PLANE_ ((size_t)CELLS_)       // c-plane stride in floats
#define BATCH_STRIDE_ ((size_t)C_ * CELLS_)        // 13,713,408 floats
#define BIN_STRIDE_   ((size_t)B_ * C_ * CELLS_)   // 54,853,632 floats
#define MAP_BIN_ ((size_t)B_ * CELLS_)             // map entries per bin

typedef float vfloat4 __attribute__((ext_vector_type(4)));
typedef int   vint4   __attribute__((ext_vector_type(4)));

// ---------------------------------------------------------------------------
// Kernel 1: scatter pillar index p into map[bin][b*CELLS + z + y*NX + x]
// coords layout per row: [b, z, y, x] int32. Cells are unique per sample.
// ---------------------------------------------------------------------------
__global__ __launch_bounds__(256) void scatter_idx_kernel(
    const int* __restrict__ coords0,
    const int* __restrict__ coords1,
    const int* __restrict__ coords2,
    int* __restrict__ map, int npil)
{
    const int bin = blockIdx.y;
    const int p = blockIdx.x * 256 + threadIdx.x;
    if (p >= npil) return;
    const int* coords = (bin == 0) ? coords0 : (bin == 1) ? coords1 : coords2;
    vint4 c = ((const vint4*)coords)[p];
    size_t idx = (size_t)bin * MAP_BIN_ + (size_t)c.x * CELLS_ + c.y + c.z * NX_ + c.w;
    map[idx] = p;
}

// ---------------------------------------------------------------------------
// Kernel 2: dense gather pass. Each thread owns 4 consecutive cells; writes
// all 64 c-planes with coalesced float4 stores (16 B/lane, contiguous 1 KB
// per wave-instruction).
//
// Round-2 change vs round-0: PLAIN stores instead of nontemporal. NT (nt
// flag) bypasses L2 write-combining; the harness's own fillBuffer proves
// plain full-line stores sustain ~6.2 TB/s with no RFO fetch. Everything
// else is identical to the 701 us round-0 kernel (single-variable A/B).
//
// Branchless loads: invalid idx (<0) is clamped to row 0 (always-safe
// address), loaded unconditionally (pipelined global_load, no exec-mask
// branches), then zero is selected in with v_cndmask AFTER the load.
// ---------------------------------------------------------------------------
__global__ __launch_bounds__(256) void gather_kernel(
    const float* __restrict__ pf0,
    const float* __restrict__ pf1,
    const float* __restrict__ pf2,
    const int* __restrict__ map,
    float* __restrict__ out)
{
    const int bin = blockIdx.z;
    const int b   = blockIdx.y;
    const int cell = blockIdx.x * 1024 + threadIdx.x * 4;
    if (cell >= CELLS_) return;

    const float* __restrict__ pf = (bin == 0) ? pf0 : (bin == 1) ? pf1 : pf2;

    const int* m = map + (size_t)bin * MAP_BIN_ + (size_t)b * CELLS_ + cell;
    vint4 idx = *(const vint4*)m;

    const bool v0 = idx.x >= 0, v1 = idx.y >= 0, v2 = idx.z >= 0, v3 = idx.w >= 0;
    // Clamp to row 0 so the address is always in-bounds -> unconditional loads.
    const float* r0 = pf + (size_t)(v0 ? idx.x : 0) * C_;
    const float* r1 = pf + (size_t)(v1 ? idx.y : 0) * C_;
    const float* r2 = pf + (size_t)(v2 ? idx.z : 0) * C_;
    const float* r3 = pf + (size_t)(v3 ? idx.w : 0) * C_;

    float* o = out + (size_t)bin * BIN_STRIDE_ + (size_t)b * BATCH_STRIDE_ + cell;

#pragma unroll 4
    for (int c = 0; c < C_; ++c) {
        // Unconditional loads (pipeline under vmcnt), select after.
        float x0 = r0[c];
        float x1 = r1[c];
        float x2 = r2[c];
        float x3 = r3[c];
        vfloat4 v;
        v.x = v0 ? x0 : 0.0f;
        v.y = v1 ? x1 : 0.0f;
        v.z = v2 ? x2 : 0.0f;
        v.w = v3 ? x3 : 0.0f;
        *(vfloat4*)(o + (size_t)c * PLANE_) = v;   // plain store: L2 write-combine
    }
}

extern "C" void kernel_launch(void* const* d_in, const int* in_sizes, int n_in,
                              void* d_out, int out_size, void* d_ws, size_t ws_size,
                              hipStream_t stream) {
    const float* pf0 = (const float*)d_in[0];
    const int*   co0 = (const int*)d_in[1];
    const float* pf1 = (const float*)d_in[2];
    const int*   co1 = (const int*)d_in[3];
    const float* pf2 = (const float*)d_in[4];
    const int*   co2 = (const int*)d_in[5];
    float* out = (float*)d_out;

    const int npil = in_sizes[1] / 4;   // rows in coords (B*P_PER)

    int* map = (int*)d_ws;
    const size_t map_bytes = 3 * MAP_BIN_ * sizeof(int);

    // init map to -1 (0xFFFFFFFF) — ~10 MB, ~2 us
    (void)hipMemsetAsync(map, 0xFF, map_bytes, stream);

    dim3 g1((npil + 255) / 256, 3, 1);
    scatter_idx_kernel<<<g1, 256, 0, stream>>>(co0, co1, co2, map, npil);

    dim3 g2((CELLS_ + 1023) / 1024, B_, 3);
    gather_kernel<<<g2, 256, 0, stream>>>(pf0, pf1, pf2, map, out);
}